// Round 1
// baseline (183.738 us; speedup 1.0000x reference)
//
#include <hip/hip_runtime.h>
#include <hip/hip_bf16.h>

// ---------------- types & helpers ----------------
typedef short bf16x8 __attribute__((ext_vector_type(8)));
typedef float f32x4  __attribute__((ext_vector_type(4)));
typedef unsigned short u16x4 __attribute__((ext_vector_type(4)));

#define CDIM   768
#define NQKV   2304
#define MROWS  8192
#define TSEQ   2048
#define HD     64
#define NHEAD  12
#define BHTOT  48

__device__ __forceinline__ unsigned short f2bf(float f) {
    unsigned int x;
    __builtin_memcpy(&x, &f, 4);
    unsigned int r = (x + 0x7fffu + ((x >> 16) & 1u)) >> 16;
    return (unsigned short)r;
}

__device__ __forceinline__ unsigned int pkbf(float a, float b) {
    unsigned int ua, ub;
    __builtin_memcpy(&ua, &a, 4);
    __builtin_memcpy(&ub, &b, 4);
    return __builtin_amdgcn_perm(ua + 0x8000u, ub + 0x8000u, 0x03020706u);
}

__device__ __forceinline__ f32x4 mfma16(bf16x8 a, bf16x8 b, f32x4 c) {
    return __builtin_amdgcn_mfma_f32_16x16x32_bf16(a, b, c, 0, 0, 0);
}

__device__ __forceinline__ void gl_lds16(const unsigned short* g, unsigned short* l) {
    __builtin_amdgcn_global_load_lds(
        (__attribute__((address_space(1))) void*)(g),
        (__attribute__((address_space(3))) void*)(l),
        16, 0, 0);
}

// ---------------- kernel 0: prep = W transpose+cvt + X cvt ----------------
__global__ __launch_bounds__(256) void prep(
    const float* __restrict__ X, const float* __restrict__ W,
    unsigned short* __restrict__ Xb, unsigned short* __restrict__ Wt)
{
    const int tid = threadIdx.x, blk = blockIdx.x;
    if (blk < 432) {
        __shared__ __align__(16) unsigned short tile[64][72];
        const int bx = blk % 36, by = blk / 36;
#pragma unroll
        for (int c = 0; c < 4; c++) {
            int chunk = tid + 256 * c;
            int r = chunk >> 4, cc = chunk & 15;
            f32x4 v = *(const f32x4*)(W + (size_t)(by * 64 + r) * NQKV + bx * 64 + cc * 4);
#pragma unroll
            for (int j = 0; j < 4; j++) tile[cc * 4 + j][r] = f2bf(v[j]);
        }
        __syncthreads();
#pragma unroll
        for (int c = 0; c < 2; c++) {
            int chunk = tid + 256 * c;
            int r = chunk >> 3, cc = chunk & 7;
            bf16x8 v;
#pragma unroll
            for (int j = 0; j < 8; j++) v[j] = (short)tile[r][cc * 8 + j];
            *(bf16x8*)(Wt + (size_t)(bx * 64 + r) * CDIM + by * 64 + cc * 8) = v;
        }
    }
    for (size_t i4 = (size_t)blk * 256 + tid; i4 < (size_t)(MROWS * CDIM / 4);
         i4 += (size_t)448 * 256) {
        f32x4 v = *(const f32x4*)(X + i4 * 4);
        u16x4 o;
#pragma unroll
        for (int j = 0; j < 4; j++) o[j] = f2bf(v[j]);
        *(u16x4*)(Xb + i4 * 4) = o;
    }
}

// ---------------- kernel 1: QKV GEMM (BM=256, BN=128, BK=64, 512 thr) ----------------
// Phase-pipelined (T3+T4+T5): 3 LDS buffers (144KB, 1 block/CU), 2 K-tiles
// prefetched ahead via global_load_lds, counted s_waitcnt vmcnt(6) (never 0 in
// steady state), raw s_barrier (NOT __syncthreads -> no vmcnt(0) drain),
// setprio(1) around each 16-MFMA cluster. XOR-swizzled LDS (bank-conflict 0).
#define BK 64
#define NTILES 12

__global__ __launch_bounds__(512, 2) void qkv_gemm(
    const unsigned short* __restrict__ X,    // (8192, 768) bf16
    const unsigned short* __restrict__ Wt,   // (2304, 768) bf16
    const float* __restrict__ Bias,          // (2304) fp32
    unsigned short* __restrict__ Q,
    unsigned short* __restrict__ Km,
    unsigned short* __restrict__ Vt)
{
    __shared__ __align__(16) unsigned short As[3 * 256 * BK];  // 96 KB
    __shared__ __align__(16) unsigned short Bs[3 * 128 * BK];  // 48 KB
    const int tid  = threadIdx.x;
    const int wave = tid >> 6, lane = tid & 63;
    const int quad = lane >> 4, m16 = lane & 15;
    const int wr = wave >> 1, wc = wave & 1;   // wr: 0..3 (64-row), wc: 0..1 (64-col)

    const int t   = blockIdx.x;                // 0..575
    const int xcd = t & 7, s = t >> 3;         // s: 0..71
    const int m0  = (xcd * 4 + (s & 3)) * 256;
    const int n0  = (s >> 2) * 128;

    f32x4 acc[4][4];
#pragma unroll
    for (int i = 0; i < 4; i++)
#pragma unroll
        for (int j = 0; j < 4; j++) acc[i][j] = f32x4{0.f, 0.f, 0.f, 0.f};

    const unsigned short* xb = X + (size_t)m0 * CDIM;
    const unsigned short* wb = Wt + (size_t)n0 * CDIM;

    const int spos = lane & 7;
    const int rb   = m16 & 7;

    // staging addressing (per 64-element K-tile):
    //   A: 4 chunks/thread, B: 2 chunks/thread, 16B each, XOR-swizzled source
    size_t agoff[4];
    size_t bgoff[2];
#pragma unroll
    for (int c = 0; c < 4; c++) {
        int row = (wave * 256 + c * 64 + lane) >> 3;
        agoff[c] = (size_t)row * CDIM + (spos ^ (row & 7)) * 8;
    }
#pragma unroll
    for (int c = 0; c < 2; c++) {
        int row = (wave * 128 + c * 64 + lane) >> 3;
        bgoff[c] = (size_t)row * CDIM + (spos ^ (row & 7)) * 8;
    }
    unsigned short* aDst = As + wave * 2048;  // + buf*16384 + c*512 (wave-uniform)
    unsigned short* bDst = Bs + wave * 1024;  // + buf*8192  + c*512

    // fragment read offsets (elements), swizzle-matched to staging
    const int posk0 = (quad ^ rb) * 8;         // ks=0
    const int posk1 = ((4 + quad) ^ rb) * 8;   // ks=1
    int arof[4], brof[4];
#pragma unroll
    for (int u = 0; u < 4; u++) arof[u] = (wr * 64 + u * 16 + m16) * 64;
#pragma unroll
    for (int j = 0; j < 4; j++) brof[j] = (wc * 64 + j * 16 + m16) * 64;

    // ---- prologue: stage tiles 0 (buf0) and 1 (buf1); 12 loads in flight ----
    gl_lds16(xb + agoff[0], aDst);
    gl_lds16(xb + agoff[1], aDst + 512);
    gl_lds16(xb + agoff[2], aDst + 1024);
    gl_lds16(xb + agoff[3], aDst + 1536);
    gl_lds16(wb + bgoff[0], bDst);
    gl_lds16(wb + bgoff[1], bDst + 512);
    gl_lds16(xb + agoff[0] + 64, aDst + 16384);
    gl_lds16(xb + agoff[1] + 64, aDst + 16384 + 512);
    gl_lds16(xb + agoff[2] + 64, aDst + 16384 + 1024);
    gl_lds16(xb + agoff[3] + 64, aDst + 16384 + 1536);
    gl_lds16(wb + bgoff[0] + 64, bDst + 8192);
    gl_lds16(wb + bgoff[1] + 64, bDst + 8192 + 512);
    asm volatile("s_waitcnt vmcnt(6)" ::: "memory");   // tile 0 resident
    __builtin_amdgcn_s_barrier();

    int qb = 0, qn = 2;   // read buffer = tt%3, prefetch buffer = (tt+2)%3
#pragma unroll 1
    for (int tt = 0; tt < NTILES; ++tt) {
        const unsigned short* Aq = As + qb * 16384;
        const unsigned short* Bq = Bs + qb * 8192;
        const int kn = (tt + 2) * 64;
        const bool st = (tt < NTILES - 2);

        // ===== phase A: ks=0 (16 MFMA) + prefetch A(t+2) =====
        bf16x8 a0[4], bA[4];
#pragma unroll
        for (int u = 0; u < 4; u++)
            a0[u] = *(const bf16x8*)(Aq + arof[u] + posk0);
#pragma unroll
        for (int j = 0; j < 4; j++)
            bA[j] = *(const bf16x8*)(Bq + brof[j] + posk0);
        if (st) {
            gl_lds16(xb + agoff[0] + kn, aDst + qn * 16384);
            gl_lds16(xb + agoff[1] + kn, aDst + qn * 16384 + 512);
            gl_lds16(xb + agoff[2] + kn, aDst + qn * 16384 + 1024);
            gl_lds16(xb + agoff[3] + kn, aDst + qn * 16384 + 1536);
        }
        __builtin_amdgcn_s_barrier();
        asm volatile("s_waitcnt lgkmcnt(0)" ::: "memory");
        __builtin_amdgcn_s_setprio(1);
#pragma unroll
        for (int i = 0; i < 4; i++)
#pragma unroll
            for (int j = 0; j < 4; j++)
                acc[i][j] = mfma16(a0[i], bA[j], acc[i][j]);
        __builtin_amdgcn_s_setprio(0);
        __builtin_amdgcn_s_barrier();

        // ===== phase B: ks=1 (16 MFMA) + prefetch B(t+2) + counted vmcnt =====
        bf16x8 a1[4], bB[4];
#pragma unroll
        for (int u = 0; u < 4; u++)
            a1[u] = *(const bf16x8*)(Aq + arof[u] + posk1);
#pragma unroll
        for (int j = 0; j < 4; j++)
            bB[j] = *(const bf16x8*)(Bq + brof[j] + posk1);
        if (st) {
            gl_lds16(wb + bgoff[0] + kn, bDst + qn * 8192);
            gl_lds16(wb + bgoff[1] + kn, bDst + qn * 8192 + 512);
        }
        // guarantee tile tt+1 resident; leave tile tt+2's 6 loads in flight
        if (tt < NTILES - 2) {
            asm volatile("s_waitcnt vmcnt(6)" ::: "memory");
        } else if (tt == NTILES - 2) {
            asm volatile("s_waitcnt vmcnt(0)" ::: "memory");
        }
        __builtin_amdgcn_s_barrier();
        asm volatile("s_waitcnt lgkmcnt(0)" ::: "memory");
        __builtin_amdgcn_s_setprio(1);
#pragma unroll
        for (int i = 0; i < 4; i++)
#pragma unroll
            for (int j = 0; j < 4; j++)
                acc[i][j] = mfma16(a1[i], bB[j], acc[i][j]);
        __builtin_amdgcn_s_setprio(0);
        __builtin_amdgcn_s_barrier();

        qb = (qb == 2) ? 0 : qb + 1;
        qn = (qn == 2) ? 0 : qn + 1;
    }

    // ---- epilogue (unchanged) ----
    const int region = n0 / CDIM;
    const float qscale = (region == 0) ? 0.125f : 1.0f;
#pragma unroll
    for (int i = 0; i < 4; i++) {
        int row = m0 + wr * 64 + i * 16 + quad * 4;
#pragma unroll
        for (int j = 0; j < 4; j++) {
            int gcol = n0 + wc * 64 + j * 16 + m16;
            int cc = gcol - region * CDIM;
            int h = cc >> 6, d = cc & 63;
            float bv = Bias[gcol];
#pragma unroll
            for (int r = 0; r < 4; r++) {
                int gm = row + r;
                int b = gm >> 11, tq = gm & 2047;
                int bh = b * NHEAD + h;
                unsigned short o = f2bf((acc[i][j][r] + bv) * qscale);
                if (region == 0)      Q[((size_t)bh * TSEQ + tq) * HD + d] = o;
                else if (region == 1) Km[((size_t)bh * TSEQ + tq) * HD + d] = o;
                else                  Vt[((size_t)bh * HD + d) * TSEQ + tq] = o;
            }
        }
    }
}

// ---------------- kernel 2: causal relu-attention (S^T formulation, R5) ----------------
#define LDSK 0
#define LDSV 8192

__global__ __launch_bounds__(256, 4) void attn(
    const unsigned short* __restrict__ Q,
    const unsigned short* __restrict__ Kmat,
    const unsigned short* __restrict__ Vt,
    float* __restrict__ Out)
{
    __shared__ __align__(16) unsigned short S[16384];  // K 16KB | V 16KB

    const int tid  = threadIdx.x;
    const int wave = tid >> 6, lane = tid & 63;
    const int q4 = lane >> 4, m16 = lane & 15;
    const int q8 = m16 >> 2, m3 = m16 & 3;

    const int xcd = blockIdx.x & 7;
    const int idx = blockIdx.x >> 3;        // 0..95
    const int bh  = xcd * 6 + (idx % 6);
    const int it  = 15 - (idx / 6);
    const int i0  = it * 128;

    const unsigned short* qb = Q    + (size_t)bh * TSEQ * HD;
    const unsigned short* kb = Kmat + (size_t)bh * TSEQ * HD;
    const unsigned short* vb = Vt   + (size_t)bh * HD * TSEQ;

    bf16x8 qf[2][2];
#pragma unroll
    for (int si = 0; si < 2; si++)
#pragma unroll
        for (int ks = 0; ks < 2; ks++)
            qf[si][ks] = *(const bf16x8*)(qb +
                (size_t)(i0 + wave * 32 + si * 16 + m16) * HD + ks * 32 + q4 * 8);

    f32x4 oacc[2][4];
#pragma unroll
    for (int si = 0; si < 2; si++)
#pragma unroll
        for (int dn = 0; dn < 4; dn++) oacc[si][dn] = f32x4{0.f, 0.f, 0.f, 0.f};

    const int fr  = ((q8 & 1) << 2) | m3;
    const int kx0 = (q4 ^ fr) * 8;
    const int kx1 = kx0 ^ 32;
    const int krb = (q8 * 8 + m3) * 64;

    for (int jt = 0; jt <= it; jt++) {
        const int j0 = jt * 128;
#pragma unroll
        for (int cc = 0; cc < 4; cc++) {
            int cs = wave * 4 + cc;
            {
                int rowK = cs * 8 + (lane >> 3);
                int chK  = (lane & 7) ^ ((((rowK >> 3) & 1) << 2) | (rowK & 3));
                gl_lds16(kb + (size_t)(j0 + rowK) * HD + chK * 8, &S[LDSK] + cs * 512);
            }
            {
                int dV  = cs * 4 + (lane >> 4);
                int chV = (m16 & 8) | ((m16 ^ dV) & 7);
                gl_lds16(vb + (size_t)dV * TSEQ + j0 + chV * 8, &S[LDSV] + cs * 512);
            }
        }
        __syncthreads();

        const bool diag = (jt == it);
#pragma unroll
        for (int kk = 0; kk < 4; kk++) {
            const int kb0 = kk * 2048 + krb;
            bf16x8 kf_e0 = *(const bf16x8*)(&S[LDSK] + kb0 + kx0);
            bf16x8 kf_e1 = *(const bf16x8*)(&S[LDSK] + kb0 + kx1);
            bf16x8 kf_o0 = *(const bf16x8*)(&S[LDSK] + kb0 + 256 + kx0);
            bf16x8 kf_o1 = *(const bf16x8*)(&S[LDSK] + kb0 + 256 + kx1);

            f32x4 sacc[2][2];
#pragma unroll
            for (int o = 0; o < 2; o++)
#pragma unroll
                for (int si = 0; si < 2; si++) sacc[o][si] = f32x4{0.f, 0.f, 0.f, 0.f};
#pragma unroll
            for (int si = 0; si < 2; si++) {
                sacc[0][si] = mfma16(kf_e0, qf[si][0], sacc[0][si]);
                sacc[0][si] = mfma16(kf_e1, qf[si][1], sacc[0][si]);
                sacc[1][si] = mfma16(kf_o0, qf[si][0], sacc[1][si]);
                sacc[1][si] = mfma16(kf_o1, qf[si][1], sacc[1][si]);
            }

            unsigned int pk[2][2][2];
#pragma unroll
            for (int o = 0; o < 2; o++)
#pragma unroll
                for (int si = 0; si < 2; si++) {
                    f32x4 v = sacc[o][si];
                    if (diag) {
#pragma unroll
                        for (int r = 0; r < 4; r++) {
                            int gj = kk * 32 + q4 * 8 + o * 4 + r;
                            int gi = wave * 32 + si * 16 + m16;
                            if (gj > gi) v[r] = 0.f;
                        }
                    }
#pragma unroll
                    for (int r = 0; r < 4; r++) v[r] = fmaxf(v[r], 0.f);
                    pk[o][si][0] = pkbf(v[0], v[1]);
                    pk[o][si][1] = pkbf(v[2], v[3]);
                }

#pragma unroll
            for (int dn = 0; dn < 4; dn++) {
                int vsw = ((kk * 4 + q4) ^ (m16 & 7)) * 8;
                bf16x8 vf = *(const bf16x8*)(&S[LDSV] + (dn * 16 + m16) * 128 + vsw);
#pragma unroll
                for (int si = 0; si < 2; si++) {
                    union { bf16x8 v; unsigned int u[4]; } af;
                    af.u[0] = pk[0][si][0];
                    af.u[1] = pk[0][si][1];
                    af.u[2] = pk[1][si][0];
                    af.u[3] = pk[1][si][1];
                    oacc[si][dn] = mfma16(af.v, vf, oacc[si][dn]);
                }
            }
        }
        __syncthreads();
    }

    const int b = bh / NHEAD, h = bh % NHEAD;
#pragma unroll
    for (int si = 0; si < 2; si++) {
        int ri = i0 + wave * 32 + si * 16 + q4 * 4;
#pragma unroll
        for (int dn = 0; dn < 4; dn++) {
            int d = dn * 16 + m16;
#pragma unroll
            for (int r = 0; r < 4; r++) {
                Out[((size_t)b * TSEQ + ri + r) * CDIM + h * HD + d] = oacc[si][dn][r];
            }
        }
    }
}

// ---------------- launch ----------------
extern "C" void kernel_launch(void* const* d_in, const int* in_sizes, int n_in,
                              void* d_out, int out_size, void* d_ws, size_t ws_size,
                              hipStream_t stream) {
    const float* X    = (const float*)d_in[0];
    const float* W    = (const float*)d_in[1];
    const float* Bias = (const float*)d_in[2];
    float* out = (float*)d_out;

    unsigned short* Xb = (unsigned short*)d_ws;
    unsigned short* Wt = Xb + (size_t)MROWS * CDIM;
    unsigned short* Q  = Wt + (size_t)NQKV * CDIM;
    unsigned short* Km = Q  + (size_t)BHTOT * TSEQ * HD;
    unsigned short* Vt = Km + (size_t)BHTOT * TSEQ * HD;

    hipLaunchKernelGGL(prep, dim3(448), dim3(256), 0, stream, X, W, Xb, Wt);
    hipLaunchKernelGGL(qkv_gemm, dim3(576), dim3(512), 0, stream,
                       Xb, Wt, Bias, Q, Km, Vt);
    hipLaunchKernelGGL(attn, dim3(BHTOT * 16), dim3(256), 0, stream, Q, Km, Vt, out);
}

// Round 2
// 183.209 us; speedup vs baseline: 1.0029x; 1.0029x over previous
//
#include <hip/hip_runtime.h>
#include <hip/hip_bf16.h>

// ---------------- types & helpers ----------------
typedef short bf16x8 __attribute__((ext_vector_type(8)));
typedef float f32x4  __attribute__((ext_vector_type(4)));
typedef unsigned short u16x4 __attribute__((ext_vector_type(4)));

#define CDIM   768
#define NQKV   2304
#define MROWS  8192
#define TSEQ   2048
#define HD     64
#define NHEAD  12
#define BHTOT  48

__device__ __forceinline__ unsigned short f2bf(float f) {
    unsigned int x;
    __builtin_memcpy(&x, &f, 4);
    unsigned int r = (x + 0x7fffu + ((x >> 16) & 1u)) >> 16;
    return (unsigned short)r;
}

__device__ __forceinline__ unsigned int pkbf(float a, float b) {
    unsigned int ua, ub;
    __builtin_memcpy(&ua, &a, 4);
    __builtin_memcpy(&ub, &b, 4);
    return __builtin_amdgcn_perm(ua + 0x8000u, ub + 0x8000u, 0x03020706u);
}

__device__ __forceinline__ f32x4 mfma16(bf16x8 a, bf16x8 b, f32x4 c) {
    return __builtin_amdgcn_mfma_f32_16x16x32_bf16(a, b, c, 0, 0, 0);
}

__device__ __forceinline__ void gl_lds16(const unsigned short* g, unsigned short* l) {
    __builtin_amdgcn_global_load_lds(
        (__attribute__((address_space(1))) void*)(g),
        (__attribute__((address_space(3))) void*)(l),
        16, 0, 0);
}

// ---------------- kernel 0: prep = W transpose+cvt + X cvt ----------------
__global__ __launch_bounds__(256) void prep(
    const float* __restrict__ X, const float* __restrict__ W,
    unsigned short* __restrict__ Xb, unsigned short* __restrict__ Wt)
{
    const int tid = threadIdx.x, blk = blockIdx.x;
    if (blk < 432) {
        __shared__ __align__(16) unsigned short tile[64][72];
        const int bx = blk % 36, by = blk / 36;
#pragma unroll
        for (int c = 0; c < 4; c++) {
            int chunk = tid + 256 * c;
            int r = chunk >> 4, cc = chunk & 15;
            f32x4 v = *(const f32x4*)(W + (size_t)(by * 64 + r) * NQKV + bx * 64 + cc * 4);
#pragma unroll
            for (int j = 0; j < 4; j++) tile[cc * 4 + j][r] = f2bf(v[j]);
        }
        __syncthreads();
#pragma unroll
        for (int c = 0; c < 2; c++) {
            int chunk = tid + 256 * c;
            int r = chunk >> 3, cc = chunk & 7;
            bf16x8 v;
#pragma unroll
            for (int j = 0; j < 8; j++) v[j] = (short)tile[r][cc * 8 + j];
            *(bf16x8*)(Wt + (size_t)(bx * 64 + r) * CDIM + by * 64 + cc * 8) = v;
        }
    }
    for (size_t i4 = (size_t)blk * 256 + tid; i4 < (size_t)(MROWS * CDIM / 4);
         i4 += (size_t)448 * 256) {
        f32x4 v = *(const f32x4*)(X + i4 * 4);
        u16x4 o;
#pragma unroll
        for (int j = 0; j < 4; j++) o[j] = f2bf(v[j]);
        *(u16x4*)(Xb + i4 * 4) = o;
    }
}

// ---------------- kernel 1: QKV GEMM (BM=256, BN=128, BK=32, 512 thr) ----------------
// Minimum-2-phase dbuf (T3 recipe, 92%-of-8ph): per tile
//   {STAGE(buf^1, t+1); ds_read buf; MFMA; vmcnt(0); s_barrier}
// vmcnt(0) lands AFTER ds_read+MFMA (~600+ cyc) so prefetch latency is hidden;
// ONE barrier per tile, no pre-compute drain. LDS 48KB (2 buf) keeps the
// baseline's multi-block/CU residency (the thing R1 lost). Swizzle re-derived
// for 64B rows: chunk ^= (row>>1)&3 (2-way bank alias = free).
#define BK 32
#define NT 24

__global__ __launch_bounds__(512, 4) void qkv_gemm(
    const unsigned short* __restrict__ X,    // (8192, 768) bf16
    const unsigned short* __restrict__ Wt,   // (2304, 768) bf16
    const float* __restrict__ Bias,          // (2304) fp32
    unsigned short* __restrict__ Q,
    unsigned short* __restrict__ Km,
    unsigned short* __restrict__ Vt)
{
    __shared__ __align__(16) unsigned short As[2 * 256 * BK];  // 32 KB
    __shared__ __align__(16) unsigned short Bs[2 * 128 * BK];  // 16 KB
    const int tid  = threadIdx.x;
    const int wave = tid >> 6, lane = tid & 63;
    const int quad = lane >> 4, m16 = lane & 15;
    const int wr = wave >> 1, wc = wave & 1;   // wr: 0..3 (64-row), wc: 0..1 (64-col)

    const int t   = blockIdx.x;                // 0..575
    const int xcd = t & 7, s = t >> 3;         // s: 0..71
    const int m0  = (xcd * 4 + (s & 3)) * 256;
    const int n0  = (s >> 2) * 128;

    f32x4 acc[4][4];
#pragma unroll
    for (int i = 0; i < 4; i++)
#pragma unroll
        for (int j = 0; j < 4; j++) acc[i][j] = f32x4{0.f, 0.f, 0.f, 0.f};

    const unsigned short* xb = X + (size_t)m0 * CDIM;
    const unsigned short* wb = Wt + (size_t)n0 * CDIM;

    // ---- staging addressing (chunk = 16B = 8 bf16; 4 chunks per 32-elem row) ----
    // A: 1024 chunks/tile, 2 per thread. B: 512 chunks/tile, 1 per thread.
    // LDS dest linear in chunk id (gl_lds requirement); global source
    // pre-swizzled: cg = cl ^ ((row>>1)&3)  [involution, matches read side].
    const unsigned short* xa0;
    const unsigned short* xa1;
    const unsigned short* wbp;
    {
        int id0 = tid;            // A chunk ids c=0
        int id1 = 512 + tid;      // A chunk ids c=1
        int r0 = id0 >> 2, cl0 = id0 & 3, cg0 = cl0 ^ ((r0 >> 1) & 3);
        int r1 = id1 >> 2, cl1 = id1 & 3, cg1 = cl1 ^ ((r1 >> 1) & 3);
        xa0 = xb + (size_t)r0 * CDIM + cg0 * 8;
        xa1 = xb + (size_t)r1 * CDIM + cg1 * 8;
        int rb = tid >> 2, clb = tid & 3, cgb = clb ^ ((rb >> 1) & 3);
        wbp = wb + (size_t)rb * CDIM + cgb * 8;
    }
    const int dA0 = wave * 512;          // + buf*8192 (elements)
    const int dA1 = 4096 + wave * 512;
    const int dB  = wave * 512;          // + buf*4096

    // ---- fragment read offsets (elements), swizzle-matched ----
    int aro[4], bro[4];
#pragma unroll
    for (int u = 0; u < 4; u++) {
        int r = wr * 64 + u * 16 + m16;
        aro[u] = r * 32 + (quad ^ ((r >> 1) & 3)) * 8;
    }
#pragma unroll
    for (int j = 0; j < 4; j++) {
        int r = wc * 64 + j * 16 + m16;
        bro[j] = r * 32 + (quad ^ ((r >> 1) & 3)) * 8;
    }

    // ---- prologue: stage tile 0 into buf 0 ----
    gl_lds16(xa0, As + dA0);
    gl_lds16(xa1, As + dA1);
    gl_lds16(wbp, Bs + dB);
    asm volatile("s_waitcnt vmcnt(0)" ::: "memory");
    __builtin_amdgcn_s_barrier();

    // ---- main loop: 24 tiles, manual 2x unroll for static buffer indices ----
#pragma unroll 1
    for (int tt = 0; tt < NT; tt += 2) {
        // --- tile tt: read buf0, prefetch (tt+1) into buf1 ---
        {
            const int kk = (tt + 1) * BK;
            gl_lds16(xa0 + kk, As + 8192 + dA0);
            gl_lds16(xa1 + kk, As + 8192 + dA1);
            gl_lds16(wbp + kk, Bs + 4096 + dB);
            bf16x8 af[4], bfg[4];
#pragma unroll
            for (int u = 0; u < 4; u++) af[u]  = *(const bf16x8*)(As + aro[u]);
#pragma unroll
            for (int j = 0; j < 4; j++) bfg[j] = *(const bf16x8*)(Bs + bro[j]);
            __builtin_amdgcn_s_setprio(1);
#pragma unroll
            for (int i = 0; i < 4; i++)
#pragma unroll
                for (int j = 0; j < 4; j++)
                    acc[i][j] = mfma16(af[i], bfg[j], acc[i][j]);
            __builtin_amdgcn_s_setprio(0);
            asm volatile("s_waitcnt vmcnt(0)" ::: "memory");
            __builtin_amdgcn_s_barrier();
        }
        // --- tile tt+1: read buf1, prefetch (tt+2) into buf0 ---
        {
            const bool st = (tt + 2 < NT);
            if (st) {
                const int kk = (tt + 2) * BK;
                gl_lds16(xa0 + kk, As + dA0);
                gl_lds16(xa1 + kk, As + dA1);
                gl_lds16(wbp + kk, Bs + dB);
            }
            bf16x8 af[4], bfg[4];
#pragma unroll
            for (int u = 0; u < 4; u++) af[u]  = *(const bf16x8*)(As + 8192 + aro[u]);
#pragma unroll
            for (int j = 0; j < 4; j++) bfg[j] = *(const bf16x8*)(Bs + 4096 + bro[j]);
            __builtin_amdgcn_s_setprio(1);
#pragma unroll
            for (int i = 0; i < 4; i++)
#pragma unroll
                for (int j = 0; j < 4; j++)
                    acc[i][j] = mfma16(af[i], bfg[j], acc[i][j]);
            __builtin_amdgcn_s_setprio(0);
            if (st) {
                asm volatile("s_waitcnt vmcnt(0)" ::: "memory");
                __builtin_amdgcn_s_barrier();
            }
        }
    }

    // ---- epilogue (unchanged from baseline) ----
    const int region = n0 / CDIM;
    const float qscale = (region == 0) ? 0.125f : 1.0f;
#pragma unroll
    for (int i = 0; i < 4; i++) {
        int row = m0 + wr * 64 + i * 16 + quad * 4;
#pragma unroll
        for (int j = 0; j < 4; j++) {
            int gcol = n0 + wc * 64 + j * 16 + m16;
            int cc = gcol - region * CDIM;
            int h = cc >> 6, d = cc & 63;
            float bv = Bias[gcol];
#pragma unroll
            for (int r = 0; r < 4; r++) {
                int gm = row + r;
                int b = gm >> 11, tq = gm & 2047;
                int bh = b * NHEAD + h;
                unsigned short o = f2bf((acc[i][j][r] + bv) * qscale);
                if (region == 0)      Q[((size_t)bh * TSEQ + tq) * HD + d] = o;
                else if (region == 1) Km[((size_t)bh * TSEQ + tq) * HD + d] = o;
                else                  Vt[((size_t)bh * HD + d) * TSEQ + tq] = o;
            }
        }
    }
}

// ---------------- kernel 2: causal relu-attention (S^T formulation, R5) ----------------
#define LDSK 0
#define LDSV 8192

__global__ __launch_bounds__(256, 4) void attn(
    const unsigned short* __restrict__ Q,
    const unsigned short* __restrict__ Kmat,
    const unsigned short* __restrict__ Vt,
    float* __restrict__ Out)
{
    __shared__ __align__(16) unsigned short S[16384];  // K 16KB | V 16KB

    const int tid  = threadIdx.x;
    const int wave = tid >> 6, lane = tid & 63;
    const int q4 = lane >> 4, m16 = lane & 15;
    const int q8 = m16 >> 2, m3 = m16 & 3;

    const int xcd = blockIdx.x & 7;
    const int idx = blockIdx.x >> 3;        // 0..95
    const int bh  = xcd * 6 + (idx % 6);
    const int it  = 15 - (idx / 6);
    const int i0  = it * 128;

    const unsigned short* qb = Q    + (size_t)bh * TSEQ * HD;
    const unsigned short* kb = Kmat + (size_t)bh * TSEQ * HD;
    const unsigned short* vb = Vt   + (size_t)bh * HD * TSEQ;

    bf16x8 qf[2][2];
#pragma unroll
    for (int si = 0; si < 2; si++)
#pragma unroll
        for (int ks = 0; ks < 2; ks++)
            qf[si][ks] = *(const bf16x8*)(qb +
                (size_t)(i0 + wave * 32 + si * 16 + m16) * HD + ks * 32 + q4 * 8);

    f32x4 oacc[2][4];
#pragma unroll
    for (int si = 0; si < 2; si++)
#pragma unroll
        for (int dn = 0; dn < 4; dn++) oacc[si][dn] = f32x4{0.f, 0.f, 0.f, 0.f};

    const int fr  = ((q8 & 1) << 2) | m3;
    const int kx0 = (q4 ^ fr) * 8;
    const int kx1 = kx0 ^ 32;
    const int krb = (q8 * 8 + m3) * 64;

    for (int jt = 0; jt <= it; jt++) {
        const int j0 = jt * 128;
#pragma unroll
        for (int cc = 0; cc < 4; cc++) {
            int cs = wave * 4 + cc;
            {
                int rowK = cs * 8 + (lane >> 3);
                int chK  = (lane & 7) ^ ((((rowK >> 3) & 1) << 2) | (rowK & 3));
                gl_lds16(kb + (size_t)(j0 + rowK) * HD + chK * 8, &S[LDSK] + cs * 512);
            }
            {
                int dV  = cs * 4 + (lane >> 4);
                int chV = (m16 & 8) | ((m16 ^ dV) & 7);
                gl_lds16(vb + (size_t)dV * TSEQ + j0 + chV * 8, &S[LDSV] + cs * 512);
            }
        }
        __syncthreads();

        const bool diag = (jt == it);
#pragma unroll
        for (int kk = 0; kk < 4; kk++) {
            const int kb0 = kk * 2048 + krb;
            bf16x8 kf_e0 = *(const bf16x8*)(&S[LDSK] + kb0 + kx0);
            bf16x8 kf_e1 = *(const bf16x8*)(&S[LDSK] + kb0 + kx1);
            bf16x8 kf_o0 = *(const bf16x8*)(&S[LDSK] + kb0 + 256 + kx0);
            bf16x8 kf_o1 = *(const bf16x8*)(&S[LDSK] + kb0 + 256 + kx1);

            f32x4 sacc[2][2];
#pragma unroll
            for (int o = 0; o < 2; o++)
#pragma unroll
                for (int si = 0; si < 2; si++) sacc[o][si] = f32x4{0.f, 0.f, 0.f, 0.f};
#pragma unroll
            for (int si = 0; si < 2; si++) {
                sacc[0][si] = mfma16(kf_e0, qf[si][0], sacc[0][si]);
                sacc[0][si] = mfma16(kf_e1, qf[si][1], sacc[0][si]);
                sacc[1][si] = mfma16(kf_o0, qf[si][0], sacc[1][si]);
                sacc[1][si] = mfma16(kf_o1, qf[si][1], sacc[1][si]);
            }

            unsigned int pk[2][2][2];
#pragma unroll
            for (int o = 0; o < 2; o++)
#pragma unroll
                for (int si = 0; si < 2; si++) {
                    f32x4 v = sacc[o][si];
                    if (diag) {
#pragma unroll
                        for (int r = 0; r < 4; r++) {
                            int gj = kk * 32 + q4 * 8 + o * 4 + r;
                            int gi = wave * 32 + si * 16 + m16;
                            if (gj > gi) v[r] = 0.f;
                        }
                    }
#pragma unroll
                    for (int r = 0; r < 4; r++) v[r] = fmaxf(v[r], 0.f);
                    pk[o][si][0] = pkbf(v[0], v[1]);
                    pk[o][si][1] = pkbf(v[2], v[3]);
                }

#pragma unroll
            for (int dn = 0; dn < 4; dn++) {
                int vsw = ((kk * 4 + q4) ^ (m16 & 7)) * 8;
                bf16x8 vf = *(const bf16x8*)(&S[LDSV] + (dn * 16 + m16) * 128 + vsw);
#pragma unroll
                for (int si = 0; si < 2; si++) {
                    union { bf16x8 v; unsigned int u[4]; } af;
                    af.u[0] = pk[0][si][0];
                    af.u[1] = pk[0][si][1];
                    af.u[2] = pk[1][si][0];
                    af.u[3] = pk[1][si][1];
                    oacc[si][dn] = mfma16(af.v, vf, oacc[si][dn]);
                }
            }
        }
        __syncthreads();
    }

    const int b = bh / NHEAD, h = bh % NHEAD;
#pragma unroll
    for (int si = 0; si < 2; si++) {
        int ri = i0 + wave * 32 + si * 16 + q4 * 4;
#pragma unroll
        for (int dn = 0; dn < 4; dn++) {
            int d = dn * 16 + m16;
#pragma unroll
            for (int r = 0; r < 4; r++) {
                Out[((size_t)b * TSEQ + ri + r) * CDIM + h * HD + d] = oacc[si][dn][r];
            }
        }
    }
}

// ---------------- launch ----------------
extern "C" void kernel_launch(void* const* d_in, const int* in_sizes, int n_in,
                              void* d_out, int out_size, void* d_ws, size_t ws_size,
                              hipStream_t stream) {
    const float* X    = (const float*)d_in[0];
    const float* W    = (const float*)d_in[1];
    const float* Bias = (const float*)d_in[2];
    float* out = (float*)d_out;

    unsigned short* Xb = (unsigned short*)d_ws;
    unsigned short* Wt = Xb + (size_t)MROWS * CDIM;
    unsigned short* Q  = Wt + (size_t)NQKV * CDIM;
    unsigned short* Km = Q  + (size_t)BHTOT * TSEQ * HD;
    unsigned short* Vt = Km + (size_t)BHTOT * TSEQ * HD;

    hipLaunchKernelGGL(prep, dim3(448), dim3(256), 0, stream, X, W, Xb, Wt);
    hipLaunchKernelGGL(qkv_gemm, dim3(576), dim3(512), 0, stream,
                       Xb, Wt, Bias, Q, Km, Vt);
    hipLaunchKernelGGL(attn, dim3(BHTOT * 16), dim3(256), 0, stream, Q, Km, Vt, out);
}